// Round 5
// baseline (504.741 us; speedup 1.0000x reference)
//
#include <hip/hip_runtime.h>

// ---------------------------------------------------------------------------
// GatingNetworkWithTopK: h = relu(x@W1+b1); g = softmax(h@W2+b2);
// top-1 mask; out = masked / (colsum+1e-4) * 32768
//
// R3: single-plane fp16 GEMM1 (absmax ~55-65 vs threshold 149.76) - FROZEN.
// R4 (counted-vmcnt BK32): REGRESSED (m196: coarse split w/o fine interleave).
// R5: dispatch consolidation 7->3: NEUTRAL (aux time is fixed cost).
// R6: 128x256 tile, BK=32, 48KB LDS: NEUTRAL-NEGATIVE. Falsified the
//     "LDS-traffic-bound" theory (-25% ds_read/MFMA, -2.7x staging -> no
//     gain). Diagnosis: each half-phase's vmcnt(0) drains loads issued at
//     the START of the same phase (stage->drain distance ~1 compute phase
//     < load latency) and only 2 blocks/CU exist to cover the stall.
// R7: exploit R6's 48KB LDS: __launch_bounds__(256,3) -> 3 blocks/CU
//     (144KB LDS, VGPR<=170). Pure TLP fix for the latency-bound drain;
//     kernel otherwise bit-identical to R6.
// ---------------------------------------------------------------------------

typedef float f32x4 __attribute__((ext_vector_type(4)));
typedef float f32x16 __attribute__((ext_vector_type(16)));
typedef __bf16 bf16x8 __attribute__((ext_vector_type(8)));
typedef _Float16 f16x8 __attribute__((ext_vector_type(8)));
typedef unsigned short u16x4 __attribute__((ext_vector_type(4)));

#define NTOK 32768
#define DIN 1024
#define DH 2048
#define NE 16

__device__ __forceinline__ unsigned short f2bf(float f) {
  unsigned u = __float_as_uint(f);
  u += 0x7FFFu + ((u >> 16) & 1u);
  return (unsigned short)(u >> 16);
}
__device__ __forceinline__ float bf2f(unsigned short s) {
  return __uint_as_float(((unsigned)s) << 16);
}

__device__ __forceinline__ void async16(const void* g, void* s) {
  __builtin_amdgcn_global_load_lds((const __attribute__((address_space(1))) void*)g,
                                   (__attribute__((address_space(3))) void*)s, 16, 0, 0);
}

// raw drain+barrier: we control the waitcnt, not the compiler's __syncthreads
__device__ __forceinline__ void flush_barrier() {
  asm volatile("s_waitcnt vmcnt(0)\n\ts_barrier" ::: "memory");
}

// ---------------- prep: convert x, transpose+convert W1, W2 frags -----------
// block ranges: [0,16384) convert_x | [16384,18432) W1^T | [18432,18448) W2
__global__ void prep_k(const float* __restrict__ x, _Float16* __restrict__ xh,
                       const float* __restrict__ W1, _Float16* __restrict__ wh,
                       const float* __restrict__ W2, unsigned short* __restrict__ w2fh,
                       unsigned short* __restrict__ w2fl, float* __restrict__ denom,
                       unsigned int* __restrict__ cnt) {
  __shared__ float tile[32][33];
  const int b = blockIdx.x;
  if (b < 16384) {
    // ---- convert x -> fp16 ----
    size_t i = (size_t)b * 256 + threadIdx.x;
    f32x4 a = ((const f32x4*)x)[i * 2];
    f32x4 c = ((const f32x4*)x)[i * 2 + 1];
    f16x8 o;
#pragma unroll
    for (int j = 0; j < 4; ++j) {
      o[j] = (_Float16)a[j];
      o[j + 4] = (_Float16)c[j];
    }
    ((f16x8*)xh)[i] = o;
  } else if (b < 16384 + 2048) {
    // ---- transpose + convert W1 [K][N] -> [N][K] ----
    const int idx = b - 16384;
    const int nt = idx & 63;
    const int kt = idx >> 6;
    const int c = threadIdx.x & 31, r0 = threadIdx.x >> 5;
#pragma unroll
    for (int i = 0; i < 4; ++i) {
      int k = (kt << 5) + r0 + (i << 3);
      tile[r0 + (i << 3)][c] = W1[(size_t)k * DH + (nt << 5) + c];
    }
    __syncthreads();
#pragma unroll
    for (int i = 0; i < 4; ++i) {
      int n = (nt << 5) + r0 + (i << 3);
      wh[(size_t)n * DIN + (kt << 5) + c] = (_Float16)tile[c][r0 + (i << 3)];
    }
  } else {
    // ---- W2 [2048][16] -> MFMA-16x16x32 B-fragment order, hi/lo planes ----
    const int bb = b - 18432;
    const int t = bb * 256 + threadIdx.x;
    const int kstep = t >> 6, l = t & 63;
    const int q = l >> 4, e = l & 15;
    u16x4 h0, h1, l0, l1;
#pragma unroll
    for (int j = 0; j < 8; ++j) {
      float v = W2[(size_t)((kstep << 5) + (q << 3) + j) * NE + e];
      unsigned short hh = f2bf(v);
      unsigned short ll = f2bf(v - bf2f(hh));
      if (j < 4) { h0[j] = hh; l0[j] = ll; } else { h1[j - 4] = hh; l1[j - 4] = ll; }
    }
    ((u16x4*)w2fh)[t * 2] = h0;
    ((u16x4*)w2fh)[t * 2 + 1] = h1;
    ((u16x4*)w2fl)[t * 2] = l0;
    ((u16x4*)w2fl)[t * 2 + 1] = l1;
    if (bb == 0) {
      if (threadIdx.x < 16) denom[threadIdx.x] = 0.0f;
      if (threadIdx.x == 16) *cnt = 0u;
    }
  }
}

// ------------------------- fused GEMM1 + partial logits ---------------------
// Block tile 128x256, BK=32. Buffer = [A 8K | B 16K] = 24 KB; two buffers.
// A: 512 chunks of 16B (128 rows x 4), B: 1024 chunks (256 rows x 4).
// Thread t owns A chunks {t, t+256}, B chunks {t, t+256, t+512, t+768}.
// LDS chunk c holds global slot (c&3) ^ ((c>>3)&3)  [= slot ^ (row>>1)&3].
struct StageCtx {
  const _Float16* g[6];
  int off[6];
};

__device__ __forceinline__ void stage_tile(const StageCtx& c, int kt, unsigned char* base) {
#pragma unroll
  for (int i = 0; i < 6; ++i) async16(c.g[i] + (kt << 5), base + c.off[i]);
}

// one BK=32 k-tile: 2 k-subs of K=16; wave tile 64x128 -> 6 reads : 8 MFMA
__device__ __forceinline__ void compute_bk32(const unsigned char* base, f32x16 (&acc)[2][4],
                                             int warow, int wacol, int la, int half, int rs) {
  const unsigned char* sA = base;
  const unsigned char* sB = base + 8192;
#pragma unroll
  for (int s = 0; s < 2; ++s) {
    const int chunk = (s << 1) + half;
    f16x8 a[2], b[4];
#pragma unroll
    for (int i = 0; i < 2; ++i) {
      const int ra = (warow + (i << 5) + la) << 6;
      a[i] = *(const f16x8*)(sA + ra + (((chunk ^ rs) & 3) << 4));
    }
#pragma unroll
    for (int j = 0; j < 4; ++j) {
      const int rb = (wacol + (j << 5) + la) << 6;
      b[j] = *(const f16x8*)(sB + rb + (((chunk ^ rs) & 3) << 4));
    }
#pragma unroll
    for (int i = 0; i < 2; ++i)
#pragma unroll
      for (int j = 0; j < 4; ++j)
        acc[i][j] = __builtin_amdgcn_mfma_f32_32x32x16_f16(a[i], b[j], acc[i][j], 0, 0, 0);
  }
}

__global__ __launch_bounds__(256, 3) void gemm1_fused_k(
    const _Float16* __restrict__ xh, const _Float16* __restrict__ wh,
    const unsigned short* __restrict__ w2fh, const unsigned short* __restrict__ w2fl,
    const float* __restrict__ b1, _Float16* __restrict__ plogh) {
  // staging: buf0 = smem[0:24K), buf1 = smem[24K:48K). Epilogue reuses 34816B.
  // 48KB LDS -> 3 blocks/CU (144KB), the R7 change.
  __shared__ unsigned char smem[49152];
  const int t = threadIdx.x;
  const int w = t >> 6;
  const int l = t & 63;
  const int la = l & 31;
  const int half = l >> 5;
  const int rs = (la >> 1) & 3;  // (row>>1)&3: warow/wacol/u*32 are 0 mod 8
  const int rowBase = blockIdx.y << 7;  // 128 tokens
  const int colBase = blockIdx.x << 8;  // 256 hidden cols
  const int warow = (w >> 1) << 6;      // {0,64}
  const int wacol = (w & 1) << 7;       // {0,128}

  StageCtx ctx;
#pragma unroll
  for (int i = 0; i < 6; ++i) {
    if (i < 2) {
      const int c = t + (i << 8);  // [0,512)
      const int row = c >> 2;
      const int sl = (c & 3) ^ ((c >> 3) & 3);
      ctx.g[i] = xh + (size_t)(rowBase + row) * DIN + (sl << 3);
      ctx.off[i] = c << 4;
    } else {
      const int c = t + ((i - 2) << 8);  // [0,1024)
      const int row = c >> 2;
      const int sl = (c & 3) ^ ((c >> 3) & 3);
      ctx.g[i] = wh + (size_t)(colBase + row) * DIN + (sl << 3);
      ctx.off[i] = 8192 + (c << 4);
    }
  }

  f32x16 acc[2][4] = {};

  stage_tile(ctx, 0, smem);
  flush_barrier();
#pragma unroll 1
  for (int kt = 0; kt < 32; kt += 2) {
    // half A: prefetch kt+1 -> buf1 while computing kt from buf0
    stage_tile(ctx, kt + 1, smem + 24576);
    compute_bk32(smem, acc, warow, wacol, la, half, rs);
    flush_barrier();
    // half B: prefetch kt+2 -> buf0 while computing kt+1 from buf1
    if (kt + 2 < 32) stage_tile(ctx, kt + 2, smem);
    compute_bk32(smem + 24576, acc, warow, wacol, la, half, rs);
    flush_barrier();
  }

  // ---- epilogue: bias + relu (keep exact fp32 h in acc) ----
  float b1v[4];
#pragma unroll
  for (int j = 0; j < 4; ++j) b1v[j] = b1[colBase + wacol + (j << 5) + la];
#pragma unroll
  for (int i = 0; i < 2; ++i)
#pragma unroll
    for (int j = 0; j < 4; ++j)
#pragma unroll
      for (int r = 0; r < 16; ++r) acc[i][j][r] = fmaxf(acc[i][j][r] + b1v[j], 0.0f);

  f32x4 pacc[2] = {};
  const int q16 = l >> 4;
  const int e16 = l & 15;
  const int myhalf = wacol >> 7;

  // two column halves of 128; per half: hi-plane pass (hh+hl) then lo (lh)
#pragma unroll
  for (int ch = 0; ch < 2; ++ch) {
    // ---- hi plane -> LDS (stride 136 bf16 = 272B); 2 owning waves write ----
    if (myhalf == ch) {
#pragma unroll
      for (int i = 0; i < 2; ++i)
#pragma unroll
        for (int j = 0; j < 4; ++j)
#pragma unroll
          for (int r = 0; r < 16; ++r) {
            const int rowl = warow + (i << 5) + (r & 3) + ((r >> 2) << 3) + (half << 2);
            const int coll = (j << 5) + la;
            *(unsigned short*)(smem + rowl * 272 + (coll << 1)) = f2bf(acc[i][j][r]);
          }
    }
    __syncthreads();
#pragma unroll
    for (int tm = 0; tm < 2; ++tm) {
      const int tok = ((w * 2 + tm) << 4) + e16;
#pragma unroll
      for (int s = 0; s < 4; ++s) {
        bf16x8 a = *(const bf16x8*)(smem + tok * 272 + (s << 6) + (q16 << 4));
        const size_t gs = (size_t)(((colBase >> 5) + (ch << 2) + s) << 6);
        bf16x8 vbh = *(const bf16x8*)(w2fh + ((gs + l) << 3));
        bf16x8 vbl = *(const bf16x8*)(w2fl + ((gs + l) << 3));
        pacc[tm] = __builtin_amdgcn_mfma_f32_16x16x32_bf16(a, vbh, pacc[tm], 0, 0, 0);
        pacc[tm] = __builtin_amdgcn_mfma_f32_16x16x32_bf16(a, vbl, pacc[tm], 0, 0, 0);
      }
    }
    __syncthreads();
    // ---- lo plane ----
    if (myhalf == ch) {
#pragma unroll
      for (int i = 0; i < 2; ++i)
#pragma unroll
        for (int j = 0; j < 4; ++j)
#pragma unroll
          for (int r = 0; r < 16; ++r) {
            const int rowl = warow + (i << 5) + (r & 3) + ((r >> 2) << 3) + (half << 2);
            const int coll = (j << 5) + la;
            const float v = acc[i][j][r];
            *(unsigned short*)(smem + rowl * 272 + (coll << 1)) = f2bf(v - bf2f(f2bf(v)));
          }
    }
    __syncthreads();
#pragma unroll
    for (int tm = 0; tm < 2; ++tm) {
      const int tok = ((w * 2 + tm) << 4) + e16;
#pragma unroll
      for (int s = 0; s < 4; ++s) {
        bf16x8 a = *(const bf16x8*)(smem + tok * 272 + (s << 6) + (q16 << 4));
        const size_t gs = (size_t)(((colBase >> 5) + (ch << 2) + s) << 6);
        bf16x8 vbh = *(const bf16x8*)(w2fh + ((gs + l) << 3));
        pacc[tm] = __builtin_amdgcn_mfma_f32_16x16x32_bf16(a, vbh, pacc[tm], 0, 0, 0);
      }
    }
    __syncthreads();
  }

  // ---- store partial logits (fp16): plog[bx][rowBase+token][e] ----
#pragma unroll
  for (int tm = 0; tm < 2; ++tm)
#pragma unroll
    for (int r = 0; r < 4; ++r) {
      const int tokl = ((w * 2 + tm) << 4) + (q16 << 2) + r;
      plogh[((size_t)blockIdx.x << 19) + ((size_t)(rowBase + tokl) << 4) + e16] =
          (_Float16)pacc[tm][r];
    }
}

// -------- reduce partials + softmax + argmax + denom + finalize -------------
// 128 blocks x 256 threads; all blocks co-resident on 256 CUs -> device-scope
// spin barrier after denom accumulation, then finalize in-place.
__global__ void reduce_finalize_k(const _Float16* __restrict__ plogh,
                                  const float* __restrict__ b2, float* __restrict__ denom,
                                  unsigned int* __restrict__ cnt, float* __restrict__ out) {
  const int tok = blockIdx.x * 256 + threadIdx.x;
  float lg[16];
#pragma unroll
  for (int e = 0; e < 16; ++e) lg[e] = b2[e];
  for (int p = 0; p < 8; ++p) {
    const f16x8* q = (const f16x8*)(plogh + ((size_t)p << 19) + ((size_t)tok << 4));
    f16x8 v0 = q[0];
    f16x8 v1 = q[1];
#pragma unroll
    for (int j = 0; j < 8; ++j) {
      lg[j] += (float)v0[j];
      lg[8 + j] += (float)v1[j];
    }
  }
  float m = lg[0];
  int idx = 0;
#pragma unroll
  for (int e = 1; e < 16; ++e)
    if (lg[e] > m) { m = lg[e]; idx = e; }
  float se = 0.0f;
#pragma unroll
  for (int e = 0; e < 16; ++e) se += expf(lg[e] - m);
  const float pt = 1.0f / se;

  __shared__ float sden[16];
  if (threadIdx.x < 16) sden[threadIdx.x] = 0.0f;
  __syncthreads();
  atomicAdd(&sden[idx], pt);
  __syncthreads();
  if (threadIdx.x < 16) atomicAdd(&denom[threadIdx.x], sden[threadIdx.x]);
  // release: make this block's denom adds device-visible before signaling
  __threadfence();
  __syncthreads();
  if (threadIdx.x == 0) {
    atomicAdd(cnt, 1u);
    while (__hip_atomic_load(cnt, __ATOMIC_ACQUIRE, __HIP_MEMORY_SCOPE_AGENT) < gridDim.x)
      __builtin_amdgcn_s_sleep(4);
  }
  __syncthreads();
  const float dv =
      __hip_atomic_load(&denom[idx], __ATOMIC_RELAXED, __HIP_MEMORY_SCOPE_AGENT);
  const float v = pt / (dv + 1e-4f) * 32768.0f;
  f32x4* q4 = (f32x4*)(out + ((size_t)tok << 4));
#pragma unroll
  for (int g = 0; g < 4; ++g) {
    f32x4 o;
#pragma unroll
    for (int j = 0; j < 4; ++j) o[j] = ((g * 4 + j) == idx) ? v : 0.0f;
    q4[g] = o;
  }
}

// ---------------------------------------------------------------------------
extern "C" void kernel_launch(void* const* d_in, const int* in_sizes, int n_in, void* d_out,
                              int out_size, void* d_ws, size_t ws_size, hipStream_t stream) {
  (void)in_sizes; (void)n_in; (void)out_size; (void)ws_size;
  const float* x = (const float*)d_in[0];
  const float* W1 = (const float*)d_in[1];
  const float* b1 = (const float*)d_in[2];
  const float* W2 = (const float*)d_in[3];
  const float* b2 = (const float*)d_in[4];
  float* out = (float*)d_out;

  char* p = (char*)d_ws;
  _Float16* xhp = (_Float16*)p; p += (size_t)NTOK * DIN * 2;
  _Float16* whp = (_Float16*)p; p += (size_t)DH * DIN * 2;
  unsigned short* w2fh = (unsigned short*)p; p += (size_t)64 * 64 * 8 * 2;
  unsigned short* w2fl = (unsigned short*)p; p += (size_t)64 * 64 * 8 * 2;
  _Float16* plogh = (_Float16*)p; p += (size_t)8 * NTOK * NE * 2;
  float* denom = (float*)p; p += 64;
  unsigned int* cnt = (unsigned int*)p; p += 64;

  prep_k<<<18448, 256, 0, stream>>>(x, xhp, W1, whp, W2, w2fh, w2fl, denom, cnt);
  gemm1_fused_k<<<dim3(8, 256), 256, 0, stream>>>(xhp, whp, w2fh, w2fl, b1, plogh);
  reduce_finalize_k<<<128, 256, 0, stream>>>(plogh, b2, denom, cnt, out);
}

// Round 6
// 405.429 us; speedup vs baseline: 1.2450x; 1.2450x over previous
//
#include <hip/hip_runtime.h>

// ---------------------------------------------------------------------------
// GatingNetworkWithTopK: h = relu(x@W1+b1); g = softmax(h@W2+b2);
// top-1 mask; out = masked / (colsum+1e-4) * 32768
//
// R3: single-plane fp16 GEMM1 (absmax 55.5-65.5 vs thr 149.76) - FROZEN.
// R4 coarse counted-vmcnt: REGRESS (m196). R5 dispatch fusion: NEUTRAL.
// R6 LDS-traffic cut: NULL. R7 launch_bounds(256,3): SPILLED (VGPR 84,
//     WRITE 262MB scratch) - occupancy can't exceed 2 blocks at 4-wave/128reg.
// R8: 8-phase-style 256x256 schedule (T3+T4+T5, the documented regime):
//     BK=64, 8 waves (512 thr), 128KB LDS = 2 x (A32K|B32K) buffers.
//     Per K-tile: front-load ALL next-tile staging (8 gload_lds), then
//     COUNTED s_waitcnt vmcnt(8) (waits tile t only, issued 4 phases ago;
//     never 0 in main loop), barrier, then 4 phases {6 ds_read -> barrier ->
//     setprio(1) 8 MFMA setprio(0) -> barrier}. Same XOR swizzle, same
//     fragment paths, R6's verified 2-col-half epilogue. K accumulation
//     order bit-identical -> absmax must stay exactly 55.5.
// ---------------------------------------------------------------------------

typedef float f32x4 __attribute__((ext_vector_type(4)));
typedef float f32x16 __attribute__((ext_vector_type(16)));
typedef __bf16 bf16x8 __attribute__((ext_vector_type(8)));
typedef _Float16 f16x8 __attribute__((ext_vector_type(8)));
typedef unsigned short u16x4 __attribute__((ext_vector_type(4)));

#define NTOK 32768
#define DIN 1024
#define DH 2048
#define NE 16

__device__ __forceinline__ unsigned short f2bf(float f) {
  unsigned u = __float_as_uint(f);
  u += 0x7FFFu + ((u >> 16) & 1u);
  return (unsigned short)(u >> 16);
}
__device__ __forceinline__ float bf2f(unsigned short s) {
  return __uint_as_float(((unsigned)s) << 16);
}

__device__ __forceinline__ void async16(const void* g, void* s) {
  __builtin_amdgcn_global_load_lds((const __attribute__((address_space(1))) void*)g,
                                   (__attribute__((address_space(3))) void*)s, 16, 0, 0);
}

// ---------------- prep: convert x, transpose+convert W1, W2 frags -----------
// block ranges: [0,16384) convert_x | [16384,18432) W1^T | [18432,18448) W2
__global__ void prep_k(const float* __restrict__ x, _Float16* __restrict__ xh,
                       const float* __restrict__ W1, _Float16* __restrict__ wh,
                       const float* __restrict__ W2, unsigned short* __restrict__ w2fh,
                       unsigned short* __restrict__ w2fl, float* __restrict__ denom,
                       unsigned int* __restrict__ cnt) {
  __shared__ float tile[32][33];
  const int b = blockIdx.x;
  if (b < 16384) {
    // ---- convert x -> fp16 ----
    size_t i = (size_t)b * 256 + threadIdx.x;
    f32x4 a = ((const f32x4*)x)[i * 2];
    f32x4 c = ((const f32x4*)x)[i * 2 + 1];
    f16x8 o;
#pragma unroll
    for (int j = 0; j < 4; ++j) {
      o[j] = (_Float16)a[j];
      o[j + 4] = (_Float16)c[j];
    }
    ((f16x8*)xh)[i] = o;
  } else if (b < 16384 + 2048) {
    // ---- transpose + convert W1 [K][N] -> [N][K] ----
    const int idx = b - 16384;
    const int nt = idx & 63;
    const int kt = idx >> 6;
    const int c = threadIdx.x & 31, r0 = threadIdx.x >> 5;
#pragma unroll
    for (int i = 0; i < 4; ++i) {
      int k = (kt << 5) + r0 + (i << 3);
      tile[r0 + (i << 3)][c] = W1[(size_t)k * DH + (nt << 5) + c];
    }
    __syncthreads();
#pragma unroll
    for (int i = 0; i < 4; ++i) {
      int n = (nt << 5) + r0 + (i << 3);
      wh[(size_t)n * DIN + (kt << 5) + c] = (_Float16)tile[c][r0 + (i << 3)];
    }
  } else {
    // ---- W2 [2048][16] -> MFMA-16x16x32 B-fragment order, hi/lo planes ----
    const int bb = b - 18432;
    const int t = bb * 256 + threadIdx.x;
    const int kstep = t >> 6, l = t & 63;
    const int q = l >> 4, e = l & 15;
    u16x4 h0, h1, l0, l1;
#pragma unroll
    for (int j = 0; j < 8; ++j) {
      float v = W2[(size_t)((kstep << 5) + (q << 3) + j) * NE + e];
      unsigned short hh = f2bf(v);
      unsigned short ll = f2bf(v - bf2f(hh));
      if (j < 4) { h0[j] = hh; l0[j] = ll; } else { h1[j - 4] = hh; l1[j - 4] = ll; }
    }
    ((u16x4*)w2fh)[t * 2] = h0;
    ((u16x4*)w2fh)[t * 2 + 1] = h1;
    ((u16x4*)w2fl)[t * 2] = l0;
    ((u16x4*)w2fl)[t * 2 + 1] = l1;
    if (bb == 0) {
      if (threadIdx.x < 16) denom[threadIdx.x] = 0.0f;
      if (threadIdx.x == 16) *cnt = 0u;
    }
  }
}

// ------------------------- fused GEMM1 + partial logits ---------------------
// Block tile 256x256, BK=64, 8 waves (2M x 4N, wave tile 128x64).
// Two 64KB buffers: [A 32K | B 32K] at smem+0 / smem+65536.
// A/B tile = 256 rows x 128B: 2048 chunks of 16B; thread t owns chunks
// {t, t+512, t+1024, t+1536}. Chunk c -> LDS (row=c>>3, slot=c&7); content
// is global slot (c&7)^(row&7) (both-sides XOR swizzle, R3-verified).
__global__ __launch_bounds__(512, 1) void gemm1_fused_k(
    const _Float16* __restrict__ xh, const _Float16* __restrict__ wh,
    const unsigned short* __restrict__ w2fh, const unsigned short* __restrict__ w2fl,
    const float* __restrict__ b1, _Float16* __restrict__ plogh) {
  __shared__ unsigned char smem[131072];
  const int t = threadIdx.x;
  const int w = t >> 6;
  const int l = t & 63;
  const int la = l & 31;
  const int half = l >> 5;
  const int sw = l & 7;
  // bijective XCD-aware map: xcd = orig&7 owns 16 contiguous row-panels
  const int orig = blockIdx.x;
  const int idx = orig >> 3;
  const int by = ((orig & 7) << 4) | (idx & 15);  // 0..127
  const int bx = idx >> 4;                        // 0..7
  const int rowBase = by << 8;   // 256 tokens
  const int colBase = bx << 8;   // 256 hidden cols
  const int warow = (w >> 2) << 7;  // {0,128}
  const int wacol = (w & 3) << 6;   // {0,64,128,192}

  const _Float16* gA[4];
  const _Float16* gB[4];
  int offc[4];
#pragma unroll
  for (int k = 0; k < 4; ++k) {
    const int c = t + (k << 9);  // 0..2047
    const int row = c >> 3;
    const int sl = (c & 7) ^ (row & 7);
    gA[k] = xh + (size_t)(rowBase + row) * DIN + (sl << 3);
    gB[k] = wh + (size_t)(colBase + row) * DIN + (sl << 3);
    offc[k] = c << 4;
  }

  f32x16 acc[4][2] = {};

  // prologue: stage tile 0 -> buf0
#pragma unroll
  for (int k = 0; k < 4; ++k) {
    async16(gA[k], smem + offc[k]);
    async16(gB[k], smem + 32768 + offc[k]);
  }

#pragma unroll 1
  for (int kt = 0; kt < 16; ++kt) {
    const unsigned char* cb = smem + ((kt & 1) << 16);
    if (kt < 15) {
      // front-load ALL of tile kt+1's staging, then COUNTED wait on tile kt
      unsigned char* nb = smem + (((kt + 1) & 1) << 16);
#pragma unroll
      for (int k = 0; k < 4; ++k) {
        async16(gA[k] + ((kt + 1) << 6), nb + offc[k]);
        async16(gB[k] + ((kt + 1) << 6), nb + 32768 + offc[k]);
      }
      asm volatile("s_waitcnt vmcnt(8)\n\ts_barrier" ::: "memory");
    } else {
      asm volatile("s_waitcnt vmcnt(0)\n\ts_barrier" ::: "memory");
    }
    // 4 phases of {ds_read frags -> barrier -> prio MFMA -> barrier}
#pragma unroll
    for (int s = 0; s < 4; ++s) {
      const int cs = ((((s << 1) + half) ^ sw)) << 4;
      f16x8 a[4], b[2];
#pragma unroll
      for (int i = 0; i < 4; ++i)
        a[i] = *(const f16x8*)(cb + ((warow + (i << 5) + la) << 7) + cs);
#pragma unroll
      for (int j = 0; j < 2; ++j)
        b[j] = *(const f16x8*)(cb + 32768 + ((wacol + (j << 5) + la) << 7) + cs);
      asm volatile("s_barrier" ::: "memory");
      __builtin_amdgcn_s_setprio(1);
#pragma unroll
      for (int i = 0; i < 4; ++i)
#pragma unroll
        for (int j = 0; j < 2; ++j)
          acc[i][j] = __builtin_amdgcn_mfma_f32_32x32x16_f16(a[i], b[j], acc[i][j], 0, 0, 0);
      __builtin_amdgcn_s_setprio(0);
      asm volatile("s_barrier" ::: "memory");
    }
  }
  __syncthreads();

  // ---- epilogue: bias + relu (keep exact fp32 h in acc) ----
  float b1v[2];
#pragma unroll
  for (int j = 0; j < 2; ++j) b1v[j] = b1[colBase + wacol + (j << 5) + la];
#pragma unroll
  for (int i = 0; i < 4; ++i)
#pragma unroll
    for (int j = 0; j < 2; ++j)
#pragma unroll
      for (int r = 0; r < 16; ++r) acc[i][j][r] = fmaxf(acc[i][j][r] + b1v[j], 0.0f);

  f32x4 pacc[2] = {};
  const int q16 = l >> 4;
  const int e16 = l & 15;
  const int myhalf = (w & 3) >> 1;  // which 128-col half this wave owns

  // two column halves of 128; per half: hi-plane pass (hh+hl) then lo (lh)
#pragma unroll
  for (int ch = 0; ch < 2; ++ch) {
    // ---- hi plane -> LDS (256 rows, stride 136 bf16 = 272B) ----
    if (myhalf == ch) {
#pragma unroll
      for (int i = 0; i < 4; ++i)
#pragma unroll
        for (int j = 0; j < 2; ++j)
#pragma unroll
          for (int r = 0; r < 16; ++r) {
            const int rowl = warow + (i << 5) + (r & 3) + ((r >> 2) << 3) + (half << 2);
            const int coll = (wacol & 127) + (j << 5) + la;
            *(unsigned short*)(smem + rowl * 272 + (coll << 1)) = f2bf(acc[i][j][r]);
          }
    }
    __syncthreads();
#pragma unroll
    for (int tm = 0; tm < 2; ++tm) {
      const int tok = ((w * 2 + tm) << 4) + e16;
#pragma unroll
      for (int s = 0; s < 4; ++s) {
        bf16x8 a = *(const bf16x8*)(smem + tok * 272 + (s << 6) + (q16 << 4));
        const size_t gs = (size_t)(((colBase >> 5) + (ch << 2) + s) << 6);
        bf16x8 vbh = *(const bf16x8*)(w2fh + ((gs + l) << 3));
        bf16x8 vbl = *(const bf16x8*)(w2fl + ((gs + l) << 3));
        pacc[tm] = __builtin_amdgcn_mfma_f32_16x16x32_bf16(a, vbh, pacc[tm], 0, 0, 0);
        pacc[tm] = __builtin_amdgcn_mfma_f32_16x16x32_bf16(a, vbl, pacc[tm], 0, 0, 0);
      }
    }
    __syncthreads();
    // ---- lo plane ----
    if (myhalf == ch) {
#pragma unroll
      for (int i = 0; i < 4; ++i)
#pragma unroll
        for (int j = 0; j < 2; ++j)
#pragma unroll
          for (int r = 0; r < 16; ++r) {
            const int rowl = warow + (i << 5) + (r & 3) + ((r >> 2) << 3) + (half << 2);
            const int coll = (wacol & 127) + (j << 5) + la;
            const float v = acc[i][j][r];
            *(unsigned short*)(smem + rowl * 272 + (coll << 1)) = f2bf(v - bf2f(f2bf(v)));
          }
    }
    __syncthreads();
#pragma unroll
    for (int tm = 0; tm < 2; ++tm) {
      const int tok = ((w * 2 + tm) << 4) + e16;
#pragma unroll
      for (int s = 0; s < 4; ++s) {
        bf16x8 a = *(const bf16x8*)(smem + tok * 272 + (s << 6) + (q16 << 4));
        const size_t gs = (size_t)(((colBase >> 5) + (ch << 2) + s) << 6);
        bf16x8 vbh = *(const bf16x8*)(w2fh + ((gs + l) << 3));
        pacc[tm] = __builtin_amdgcn_mfma_f32_16x16x32_bf16(a, vbh, pacc[tm], 0, 0, 0);
      }
    }
    __syncthreads();
  }

  // ---- store partial logits (fp16): plog[bx][rowBase+token][e] ----
#pragma unroll
  for (int tm = 0; tm < 2; ++tm)
#pragma unroll
    for (int r = 0; r < 4; ++r) {
      const int tokl = ((w * 2 + tm) << 4) + (q16 << 2) + r;
      plogh[((size_t)bx << 19) + ((size_t)(rowBase + tokl) << 4) + e16] =
          (_Float16)pacc[tm][r];
    }
}

// -------- reduce partials + softmax + argmax + denom + finalize -------------
// 128 blocks x 256 threads; all blocks co-resident on 256 CUs -> device-scope
// spin barrier after denom accumulation, then finalize in-place.
__global__ void reduce_finalize_k(const _Float16* __restrict__ plogh,
                                  const float* __restrict__ b2, float* __restrict__ denom,
                                  unsigned int* __restrict__ cnt, float* __restrict__ out) {
  const int tok = blockIdx.x * 256 + threadIdx.x;
  float lg[16];
#pragma unroll
  for (int e = 0; e < 16; ++e) lg[e] = b2[e];
  for (int p = 0; p < 8; ++p) {
    const f16x8* q = (const f16x8*)(plogh + ((size_t)p << 19) + ((size_t)tok << 4));
    f16x8 v0 = q[0];
    f16x8 v1 = q[1];
#pragma unroll
    for (int j = 0; j < 8; ++j) {
      lg[j] += (float)v0[j];
      lg[8 + j] += (float)v1[j];
    }
  }
  float m = lg[0];
  int idx = 0;
#pragma unroll
  for (int e = 1; e < 16; ++e)
    if (lg[e] > m) { m = lg[e]; idx = e; }
  float se = 0.0f;
#pragma unroll
  for (int e = 0; e < 16; ++e) se += expf(lg[e] - m);
  const float pt = 1.0f / se;

  __shared__ float sden[16];
  if (threadIdx.x < 16) sden[threadIdx.x] = 0.0f;
  __syncthreads();
  atomicAdd(&sden[idx], pt);
  __syncthreads();
  if (threadIdx.x < 16) atomicAdd(&denom[threadIdx.x], sden[threadIdx.x]);
  // release: make this block's denom adds device-visible before signaling
  __threadfence();
  __syncthreads();
  if (threadIdx.x == 0) {
    atomicAdd(cnt, 1u);
    while (__hip_atomic_load(cnt, __ATOMIC_ACQUIRE, __HIP_MEMORY_SCOPE_AGENT) < gridDim.x)
      __builtin_amdgcn_s_sleep(4);
  }
  __syncthreads();
  const float dv =
      __hip_atomic_load(&denom[idx], __ATOMIC_RELAXED, __HIP_MEMORY_SCOPE_AGENT);
  const float v = pt / (dv + 1e-4f) * 32768.0f;
  f32x4* q4 = (f32x4*)(out + ((size_t)tok << 4));
#pragma unroll
  for (int g = 0; g < 4; ++g) {
    f32x4 o;
#pragma unroll
    for (int j = 0; j < 4; ++j) o[j] = ((g * 4 + j) == idx) ? v : 0.0f;
    q4[g] = o;
  }
}

// ---------------------------------------------------------------------------
extern "C" void kernel_launch(void* const* d_in, const int* in_sizes, int n_in, void* d_out,
                              int out_size, void* d_ws, size_t ws_size, hipStream_t stream) {
  (void)in_sizes; (void)n_in; (void)out_size; (void)ws_size;
  const float* x = (const float*)d_in[0];
  const float* W1 = (const float*)d_in[1];
  const float* b1 = (const float*)d_in[2];
  const float* W2 = (const float*)d_in[3];
  const float* b2 = (const float*)d_in[4];
  float* out = (float*)d_out;

  char* p = (char*)d_ws;
  _Float16* xhp = (_Float16*)p; p += (size_t)NTOK * DIN * 2;
  _Float16* whp = (_Float16*)p; p += (size_t)DH * DIN * 2;
  unsigned short* w2fh = (unsigned short*)p; p += (size_t)64 * 64 * 8 * 2;
  unsigned short* w2fl = (unsigned short*)p; p += (size_t)64 * 64 * 8 * 2;
  _Float16* plogh = (_Float16*)p; p += (size_t)8 * NTOK * NE * 2;
  float* denom = (float*)p; p += 64;
  unsigned int* cnt = (unsigned int*)p; p += 64;

  prep_k<<<18448, 256, 0, stream>>>(x, xhp, W1, whp, W2, w2fh, w2fl, denom, cnt);
  gemm1_fused_k<<<1024, 512, 0, stream>>>(xhp, whp, w2fh, w2fl, b1, plogh);
  reduce_finalize_k<<<128, 256, 0, stream>>>(plogh, b2, denom, cnt, out);
}